// Round 2
// baseline (210.951 us; speedup 1.0000x reference)
//
#include <hip/hip_runtime.h>
#include <math.h>

#define TOKENS  32768
#define HIDDEN  2048
#define EXPERTS 64
#define TOPK    8
#define KSPLIT  8                    // K-slices per token-group (2 blocks x 4 waves)
#define KSLICE  (HIDDEN / KSPLIT)    // 256

// ---------------------------------------------------------------------------
// Kernel 1: transpose weight [64][2048] -> wT [2048][64] so per-k the 64
// expert weights are consecutive -> wave-uniform scalar-loadable.
// ---------------------------------------------------------------------------
__global__ void wt_transpose(const float* __restrict__ W, float* __restrict__ wT) {
    int i = blockIdx.x * 256 + threadIdx.x;   // 0..131071
    int k = i >> 6;
    int e = i & 63;
    wT[i] = W[e * HIDDEN + k];
}

// ---------------------------------------------------------------------------
// Kernel 2: partial GEMM. Block = 256 threads = 4 waves. Two blocks per
// token-group; wave (blk&1)*4+w owns K-slice of 256. lane t == token.
// 64 fp32 accumulators/lane; weights via wave-uniform scalar loads; A via
// full-64B-line float4 loads, double-buffered. No LDS -> occupancy limited
// only by grid/VGPR (4 waves/SIMD). Partials written straight to d_ws.
// ---------------------------------------------------------------------------
__global__ __launch_bounds__(256, 4)
void gemm_partial(const float* __restrict__ A,
                  const float* __restrict__ wT,
                  float* __restrict__ partials) {
    const int tid = threadIdx.x;
    const int w   = tid >> 6;
    const int t   = tid & 63;
    const int group = blockIdx.x >> 1;
    const int p     = ((blockIdx.x & 1) << 2) | w;   // 0..7
    const int k0    = p * KSLICE;
    const int token = group * 64 + t;

    const float* a_row = A + (size_t)token * HIDDEN + k0;

    float acc[64];
    #pragma unroll
    for (int e = 0; e < 64; ++e) acc[e] = 0.f;

    // prime: whole 64B line (16 k's) in registers
    float4 c0 = *(const float4*)(a_row + 0);
    float4 c1 = *(const float4*)(a_row + 4);
    float4 c2 = *(const float4*)(a_row + 8);
    float4 c3 = *(const float4*)(a_row + 12);

    #pragma unroll 1
    for (int kk = 0; kk < KSLICE; kk += 16) {
        float4 n0, n1, n2, n3;
        const bool more = (kk + 16) < KSLICE;
        if (more) {
            n0 = *(const float4*)(a_row + kk + 16);
            n1 = *(const float4*)(a_row + kk + 20);
            n2 = *(const float4*)(a_row + kk + 24);
            n3 = *(const float4*)(a_row + kk + 28);
        } else {
            n0 = n1 = n2 = n3 = make_float4(0.f, 0.f, 0.f, 0.f);
        }

        int kb = __builtin_amdgcn_readfirstlane(k0 + kk);
        const float* w0 = wT + (size_t)kb * 64;

        #define FMA64(aval, off) \
            { float aj_ = (aval); const float* wp_ = w0 + (off) * 64; \
              _Pragma("unroll") \
              for (int e = 0; e < 64; ++e) acc[e] = fmaf(aj_, wp_[e], acc[e]); }

        FMA64(c0.x, 0)  FMA64(c0.y, 1)  FMA64(c0.z, 2)  FMA64(c0.w, 3)
        FMA64(c1.x, 4)  FMA64(c1.y, 5)  FMA64(c1.z, 6)  FMA64(c1.w, 7)
        FMA64(c2.x, 8)  FMA64(c2.y, 9)  FMA64(c2.z, 10) FMA64(c2.w, 11)
        FMA64(c3.x, 12) FMA64(c3.y, 13) FMA64(c3.z, 14) FMA64(c3.w, 15)
        #undef FMA64

        c0 = n0; c1 = n1; c2 = n2; c3 = n3;
    }

    // partial write: [group][p][e*64+t] -- consecutive t across lanes = coalesced
    float* dst = partials + ((size_t)group * KSPLIT + p) * 4096;
    #pragma unroll
    for (int e = 0; e < 64; ++e) dst[e * 64 + t] = acc[e];
}

// ---------------------------------------------------------------------------
// Kernel 3: reduce 8 partials + bias -> logits[64e][64t] in LDS, top-8 +
// softmax + scatter + coalesced writes. One block per 64-token group.
// ---------------------------------------------------------------------------
__global__ __launch_bounds__(256, 2)
void reduce_topk(const float* __restrict__ partials,
                 const float* __restrict__ bias,
                 float* __restrict__ out) {
    __shared__ float logits[4096];     // [e][t]
    __shared__ float scat[64 * 65];    // [t][e] padded
    const int tid = threadIdx.x;
    const int t   = tid & 63;
    const int group = blockIdx.x;

    const float* base = partials + (size_t)group * KSPLIT * 4096;

    #pragma unroll
    for (int q = 0; q < 4; ++q) {
        int i = (tid + 256 * q) * 4;             // float4-aligned, e = i>>6 const over 4
        float4 s = make_float4(0.f, 0.f, 0.f, 0.f);
        #pragma unroll
        for (int p = 0; p < KSPLIT; ++p) {
            float4 v = *(const float4*)(base + p * 4096 + i);
            s.x += v.x; s.y += v.y; s.z += v.z; s.w += v.w;
        }
        float b = bias[i >> 6];
        s.x += b; s.y += b; s.z += b; s.w += b;
        *(float4*)(logits + i) = s;
    }
    for (int i = tid; i < 64 * 65; i += 256) scat[i] = 0.f;
    __syncthreads();

    if (tid < 64) {
        float v[64];
        #pragma unroll
        for (int e = 0; e < 64; ++e) v[e] = logits[e * 64 + t];

        float tvals[TOPK]; int tix[TOPK]; float probs[TOPK];
        unsigned long long chosen = 0ull;
        #pragma unroll
        for (int j = 0; j < TOPK; ++j) {
            float best = -INFINITY; int bi = 0;
            #pragma unroll
            for (int e = 0; e < 64; ++e) {
                bool ok = ((chosen >> e) & 1ull) == 0ull;
                if (ok && v[e] > best) { best = v[e]; bi = e; }   // strict > : lowest idx on tie
            }
            chosen |= (1ull << bi);
            tvals[j] = best; tix[j] = bi;
        }
        float m = tvals[0];
        float s = 0.f;
        #pragma unroll
        for (int j = 0; j < TOPK; ++j) { probs[j] = __expf(tvals[j] - m); s += probs[j]; }
        float inv = 1.f / s;
        #pragma unroll
        for (int j = 0; j < TOPK; ++j) probs[j] *= inv;

        #pragma unroll
        for (int j = 0; j < TOPK; ++j) scat[t * 65 + tix[j]] = probs[j];

        float* oidx = out + (size_t)TOKENS * EXPERTS;
        const int token = group * 64 + t;
        #pragma unroll
        for (int j = 0; j < TOPK; ++j) oidx[(size_t)token * TOPK + j] = (float)tix[j];
    }
    __syncthreads();

    // coalesced score write: 64 tokens x 64 experts
    float* oscore = out + (size_t)group * 4096;
    #pragma unroll
    for (int q = 0; q < 4; ++q) {
        int i = tid + 256 * q;                   // float4 index 0..1023
        int tok = i >> 4;
        int e0  = (i & 15) * 4;
        float4 vv;
        vv.x = scat[tok * 65 + e0 + 0];
        vv.y = scat[tok * 65 + e0 + 1];
        vv.z = scat[tok * 65 + e0 + 2];
        vv.w = scat[tok * 65 + e0 + 3];
        *(float4*)(oscore + (size_t)i * 4) = vv;
    }
}

extern "C" void kernel_launch(void* const* d_in, const int* in_sizes, int n_in,
                              void* d_out, int out_size, void* d_ws, size_t ws_size,
                              hipStream_t stream) {
    const float* A    = (const float*)d_in[0];   // [32768, 2048] fp32
    const float* W    = (const float*)d_in[1];   // [64, 2048] fp32
    const float* bias = (const float*)d_in[2];   // [64] fp32
    float* out = (float*)d_out;                  // scores (32768*64) ++ idx (32768*8)

    float* wT       = (float*)d_ws;                    // 512 KB
    float* partials = (float*)d_ws + 131072;           // 512*8*4096 floats = 64 MB

    wt_transpose<<<512, 256, 0, stream>>>(W, wT);
    gemm_partial<<<(TOKENS / 64) * 2, 256, 0, stream>>>(A, wT, partials);
    reduce_topk<<<TOKENS / 64, 256, 0, stream>>>(partials, bias, out);
}

// Round 3
// 150.405 us; speedup vs baseline: 1.4026x; 1.4026x over previous
//
#include <hip/hip_runtime.h>
#include <math.h>

#define TOKENS  32768
#define HIDDEN  2048
#define EXPERTS 64
#define TOPK    8
#define BK      32
#define KHALF   (HIDDEN / 2)     // 1024 per in-block K-half
#define NSTEP   (KHALF / BK)     // 32 double-buffered steps

// ---------------------------------------------------------------------------
// One fused kernel. Block = 512 threads (8 waves) owns 64 tokens x 64 experts.
// Waves 0-3 compute K-half 0, waves 4-7 K-half 1; wave wv owns experts
// [wv*16, wv*16+16). Lane: 4 tokens x 4 experts register tile (reuse 4 on both
// streams). A and W tiles staged to LDS as [k][row] (transpose-on-write),
// double-buffered, weights read as 16-lane-broadcast ds_read_b128 -> no
// scalar-unit traffic in the hot loop. Epilogue: cross-half LDS reduce + bias,
// per-token top-8 + softmax + scatter, coalesced writes.
// ---------------------------------------------------------------------------
__global__ __launch_bounds__(512, 4)
void router_fused(const float* __restrict__ A,
                  const float* __restrict__ W,
                  const float* __restrict__ bias,
                  float* __restrict__ out) {
    __shared__ float smem[16384];            // 64 KB: A tiles [0,8192), W tiles [8192,16384)
    const int tid  = threadIdx.x;
    const int wave = tid >> 6;
    const int lane = tid & 63;
    const int h    = wave >> 2;              // K-half (== tid>>8)
    const int wv   = wave & 3;               // expert quadrant
    const int g    = blockIdx.x;

    // ---- staging mapping: q in [0,256) per half; row r, float4-col c4 ----
    const int q  = tid & 255;
    const int r  = q >> 2;                   // 0..63  (token row for A, expert row for W)
    const int c4 = q & 3;                    // covers k-offsets c4*4..+3 and 16+c4*4..+3
    const float* arow = A + ((size_t)(g * 64 + r)) * HIDDEN + h * KHALF;
    const float* wrow = W + (size_t)r * HIDDEN + h * KHALF;

    // ---- compute mapping ----
    const int t0 = (lane & 15) * 4;          // 4 tokens
    const int e0 = wv * 16 + (lane >> 4) * 4;// 4 experts

    float* ab0 = smem + (h * 2 + 0) * 2048;  // [32][64] A tile, buffer 0
    float* ab1 = smem + (h * 2 + 1) * 2048;
    float* wb0 = smem + 8192 + (h * 2 + 0) * 2048;
    float* wb1 = smem + 8192 + (h * 2 + 1) * 2048;

    float acc[4][4];
    #pragma unroll
    for (int i = 0; i < 4; ++i)
        #pragma unroll
        for (int j = 0; j < 4; ++j) acc[i][j] = 0.f;

    float4 la0, la1, lw0, lw1;

    #define LOADK(s) do {                                                   \
        const int k0_ = (s) * BK;                                           \
        la0 = *(const float4*)(arow + k0_ + c4 * 4);                        \
        la1 = *(const float4*)(arow + k0_ + 16 + c4 * 4);                   \
        lw0 = *(const float4*)(wrow + k0_ + c4 * 4);                        \
        lw1 = *(const float4*)(wrow + k0_ + 16 + c4 * 4);                   \
    } while (0)

    #define DSW(ab, wb) do {                                                \
        (ab)[(c4*4+0)*64 + r] = la0.x; (ab)[(c4*4+1)*64 + r] = la0.y;       \
        (ab)[(c4*4+2)*64 + r] = la0.z; (ab)[(c4*4+3)*64 + r] = la0.w;       \
        (ab)[(16+c4*4+0)*64 + r] = la1.x; (ab)[(16+c4*4+1)*64 + r] = la1.y; \
        (ab)[(16+c4*4+2)*64 + r] = la1.z; (ab)[(16+c4*4+3)*64 + r] = la1.w; \
        (wb)[(c4*4+0)*64 + r] = lw0.x; (wb)[(c4*4+1)*64 + r] = lw0.y;       \
        (wb)[(c4*4+2)*64 + r] = lw0.z; (wb)[(c4*4+3)*64 + r] = lw0.w;       \
        (wb)[(16+c4*4+0)*64 + r] = lw1.x; (wb)[(16+c4*4+1)*64 + r] = lw1.y; \
        (wb)[(16+c4*4+2)*64 + r] = lw1.z; (wb)[(16+c4*4+3)*64 + r] = lw1.w; \
    } while (0)

    #define COMPUTE(ab, wb) do {                                            \
        _Pragma("unroll")                                                   \
        for (int k = 0; k < BK; ++k) {                                      \
            float4 av  = *(const float4*)((ab) + k * 64 + t0);              \
            float4 wv4 = *(const float4*)((wb) + k * 64 + e0);              \
            float ar_[4] = {av.x, av.y, av.z, av.w};                        \
            float wr_[4] = {wv4.x, wv4.y, wv4.z, wv4.w};                    \
            _Pragma("unroll")                                               \
            for (int i = 0; i < 4; ++i)                                     \
                _Pragma("unroll")                                           \
                for (int j = 0; j < 4; ++j)                                 \
                    acc[i][j] = fmaf(ar_[i], wr_[j], acc[i][j]);            \
        }                                                                   \
    } while (0)

    // prologue: stage step 0 into buffer 0
    LOADK(0);
    DSW(ab0, wb0);

    #pragma unroll 1
    for (int s = 0; s < NSTEP; s += 2) {
        __syncthreads();                 // buf0 staged
        LOADK(s + 1);                    // issue next loads (fly during compute)
        COMPUTE(ab0, wb0);
        DSW(ab1, wb1);                   // vmcnt wait lands here, after compute
        __syncthreads();                 // buf1 staged
        if (s + 2 < NSTEP) {
            LOADK(s + 2);
            COMPUTE(ab1, wb1);
            DSW(ab0, wb0);
        } else {
            COMPUTE(ab1, wb1);
        }
    }
    #undef LOADK
    #undef DSW
    #undef COMPUTE

    __syncthreads();                     // done with tiles; alias LDS for epilogue

    float* logits = smem;                // [64 e][64 t]  (4096 floats)
    float* scat   = smem + 8192;         // [64 t][65]    (4160 floats)

    if (h == 1) {
        #pragma unroll
        for (int i = 0; i < 4; ++i)
            #pragma unroll
            for (int j = 0; j < 4; ++j)
                logits[(e0 + j) * 64 + (t0 + i)] = acc[i][j];
    }
    __syncthreads();
    if (h == 0) {
        #pragma unroll
        for (int j = 0; j < 4; ++j) {
            float b = bias[e0 + j];
            #pragma unroll
            for (int i = 0; i < 4; ++i) {
                int idx = (e0 + j) * 64 + (t0 + i);
                logits[idx] = logits[idx] + acc[i][j] + b;
            }
        }
    }
    for (int i = tid; i < 64 * 65; i += 512) scat[i] = 0.f;
    __syncthreads();

    if (tid < 64) {
        const int t = tid;
        float v[64];
        #pragma unroll
        for (int e = 0; e < 64; ++e) v[e] = logits[e * 64 + t];

        float tvals[TOPK]; int tix[TOPK]; float probs[TOPK];
        unsigned long long chosen = 0ull;
        #pragma unroll
        for (int j = 0; j < TOPK; ++j) {
            float best = -INFINITY; int bi = 0;
            #pragma unroll
            for (int e = 0; e < 64; ++e) {
                bool ok = ((chosen >> e) & 1ull) == 0ull;
                if (ok && v[e] > best) { best = v[e]; bi = e; }  // strict >: lowest idx on tie
            }
            chosen |= (1ull << bi);
            tvals[j] = best; tix[j] = bi;
        }
        float m = tvals[0];
        float ssum = 0.f;
        #pragma unroll
        for (int j = 0; j < TOPK; ++j) { probs[j] = __expf(tvals[j] - m); ssum += probs[j]; }
        float inv = 1.f / ssum;
        #pragma unroll
        for (int j = 0; j < TOPK; ++j) probs[j] *= inv;

        #pragma unroll
        for (int j = 0; j < TOPK; ++j) scat[t * 65 + tix[j]] = probs[j];

        float* oidx = out + (size_t)TOKENS * EXPERTS;
        const int token = g * 64 + t;
        #pragma unroll
        for (int j = 0; j < TOPK; ++j) oidx[(size_t)token * TOPK + j] = (float)tix[j];
    }
    __syncthreads();

    // coalesced score write: 64 tokens x 64 experts = 1024 float4s
    float* oscore = out + (size_t)g * 4096;
    #pragma unroll
    for (int p = 0; p < 2; ++p) {
        int fi  = tid + 512 * p;         // float4 index 0..1023
        int tok = fi >> 4;
        int es  = (fi & 15) * 4;
        float4 vv;
        vv.x = scat[tok * 65 + es + 0];
        vv.y = scat[tok * 65 + es + 1];
        vv.z = scat[tok * 65 + es + 2];
        vv.w = scat[tok * 65 + es + 3];
        *(float4*)(oscore + (size_t)fi * 4) = vv;
    }
}

extern "C" void kernel_launch(void* const* d_in, const int* in_sizes, int n_in,
                              void* d_out, int out_size, void* d_ws, size_t ws_size,
                              hipStream_t stream) {
    const float* A    = (const float*)d_in[0];   // [32768, 2048] fp32
    const float* W    = (const float*)d_in[1];   // [64, 2048] fp32
    const float* bias = (const float*)d_in[2];   // [64] fp32
    float* out = (float*)d_out;                  // scores (32768*64) ++ idx (32768*8)

    router_fused<<<TOKENS / 64, 512, 0, stream>>>(A, W, bias, out);
}